// Round 1
// baseline (615.332 us; speedup 1.0000x reference)
//
#include <hip/hip_runtime.h>
#include <hip/hip_bf16.h>

#define Bsz 2
#define Tsz 2048
#define Csz 1024
#define Hn 16
#define HDs 64

typedef short s8v __attribute__((ext_vector_type(8)));
typedef float f4v __attribute__((ext_vector_type(4)));

__device__ __forceinline__ short bf_bits(float x) {
    __hip_bfloat16 t = __float2bfloat16(x);
    return *reinterpret_cast<short*>(&t);
}

// ---------------- fp32 -> bf16 conversion ----------------
__global__ void cvt_kernel(const float* __restrict__ in, short* __restrict__ out, int n) {
    int i = (blockIdx.x * blockDim.x + threadIdx.x) * 4;
    if (i >= n) return;
    float4 v = *(const float4*)(in + i);
    short4 o;
    o.x = bf_bits(v.x); o.y = bf_bits(v.y); o.z = bf_bits(v.z); o.w = bf_bits(v.w);
    *(short4*)(out + i) = o;
}

// ---------------- GEMM: out[m,n] = sum_k A[m,k]*W[n,k] + bias[n] ----------------
// A: [M,K] bf16 (as short), W: [N,K] bf16, bias fp32.
// Block = 256 threads (4 waves); block tile 64m x 64n; wave computes 16m x 64n.
template<int F32OUT>
__global__ __launch_bounds__(256) void gemm_bias_kernel(
    const short* __restrict__ A, const short* __restrict__ W,
    const float* __restrict__ bias, void* __restrict__ outp,
    int M, int N, int K)
{
    const int wave = threadIdx.x >> 6, lane = threadIdx.x & 63;
    const int ln = lane & 15, hi = lane >> 4;
    const int m0 = blockIdx.x * 64 + wave * 16;
    const int n0 = blockIdx.y * 64;

    const s8v* Arow = (const s8v*)(A + (size_t)(m0 + ln) * K);
    const s8v* W0 = (const s8v*)(W + (size_t)(n0 + ln) * K);
    const s8v* W1 = (const s8v*)(W + (size_t)(n0 + 16 + ln) * K);
    const s8v* W2 = (const s8v*)(W + (size_t)(n0 + 32 + ln) * K);
    const s8v* W3 = (const s8v*)(W + (size_t)(n0 + 48 + ln) * K);

    f4v acc[4];
    #pragma unroll
    for (int nt = 0; nt < 4; nt++)
        #pragma unroll
        for (int i = 0; i < 4; i++) acc[nt][i] = 0.f;

    const int kv8 = K / 8;
    #pragma unroll 4
    for (int k8 = 0; k8 < kv8; k8 += 4) {
        s8v a = Arow[k8 + hi];
        acc[0] = __builtin_amdgcn_mfma_f32_16x16x32_bf16(a, W0[k8 + hi], acc[0], 0, 0, 0);
        acc[1] = __builtin_amdgcn_mfma_f32_16x16x32_bf16(a, W1[k8 + hi], acc[1], 0, 0, 0);
        acc[2] = __builtin_amdgcn_mfma_f32_16x16x32_bf16(a, W2[k8 + hi], acc[2], 0, 0, 0);
        acc[3] = __builtin_amdgcn_mfma_f32_16x16x32_bf16(a, W3[k8 + hi], acc[3], 0, 0, 0);
    }

    #pragma unroll
    for (int nt = 0; nt < 4; nt++) {
        const int col = n0 + nt * 16 + ln;
        const float bv = bias[col];
        #pragma unroll
        for (int i = 0; i < 4; i++) {
            const int row = m0 + hi * 4 + i;
            const float v = acc[nt][i] + bv;
            if (F32OUT) ((float*)outp)[(size_t)row * N + col] = v;
            else        ((short*)outp)[(size_t)row * N + col] = bf_bits(v);
        }
    }
}

// ---------------- Flash attention (causal) ----------------
// Q,K,V,Y: [B,T,C] bf16 (head h at channel offset h*64).
// Grid: (T/64, B*H); 256 threads = 4 waves; wave owns 16 q-rows.
__global__ __launch_bounds__(256) void attn_kernel(
    const short* __restrict__ Q, const short* __restrict__ K,
    const short* __restrict__ V, short* __restrict__ Y)
{
    __shared__ __align__(16) short Ksh[32 * 64];   // [key][d]
    __shared__ __align__(16) short Vsh[64 * 32];   // transposed: [d][key]
    __shared__ __align__(16) short Psh[4 * 16 * 32]; // per-wave P tile [q][key]

    const int tid = threadIdx.x;
    const int wave = tid >> 6, lane = tid & 63;
    const int ln = lane & 15, hi = lane >> 4;
    const int b = blockIdx.y >> 4, h = blockIdx.y & 15;
    const int qt = blockIdx.x;
    const int q0 = qt * 64 + wave * 16;
    const size_t base = (size_t)b * Tsz * Csz + h * HDs;

    // Q fragments (A-operand layout), kept in registers for the whole kernel.
    s8v qa0 = *(const s8v*)(Q + base + (size_t)(q0 + ln) * Csz + hi * 8);
    s8v qa1 = *(const s8v*)(Q + base + (size_t)(q0 + ln) * Csz + 32 + hi * 8);

    f4v o[4];
    float m_i[4], l_i[4];
    #pragma unroll
    for (int i = 0; i < 4; i++) {
        m_i[i] = -__builtin_inff(); l_i[i] = 0.f;
        o[0][i] = 0.f; o[1][i] = 0.f; o[2][i] = 0.f; o[3][i] = 0.f;
    }

    const int sr = tid >> 3;        // staging row 0..31
    const int sc = (tid & 7) * 8;   // staging col

    const int nkb = qt * 2 + 2;     // causal: key blocks of 32 up to q-tile end
    for (int kb = 0; kb < nkb; kb++) {
        const int k0 = kb * 32;
        __syncthreads();
        // stage K block [32 x 64]
        s8v kv = *(const s8v*)(K + base + (size_t)(k0 + sr) * Csz + sc);
        *(s8v*)(Ksh + sr * 64 + sc) = kv;
        // stage V block transposed [64 x 32]
        s8v vv = *(const s8v*)(V + base + (size_t)(k0 + sr) * Csz + sc);
        #pragma unroll
        for (int j = 0; j < 8; j++) Vsh[(sc + j) * 32 + sr] = vv[j];
        __syncthreads();

        // S = Q * K^T for two 16-key subtiles
        f4v s0, s1;
        #pragma unroll
        for (int i = 0; i < 4; i++) { s0[i] = 0.f; s1[i] = 0.f; }
        {
            s8v kf0 = *(const s8v*)(Ksh + ln * 64 + hi * 8);
            s0 = __builtin_amdgcn_mfma_f32_16x16x32_bf16(qa0, kf0, s0, 0, 0, 0);
            s8v kf1 = *(const s8v*)(Ksh + ln * 64 + 32 + hi * 8);
            s0 = __builtin_amdgcn_mfma_f32_16x16x32_bf16(qa1, kf1, s0, 0, 0, 0);
            s8v kf2 = *(const s8v*)(Ksh + (16 + ln) * 64 + hi * 8);
            s1 = __builtin_amdgcn_mfma_f32_16x16x32_bf16(qa0, kf2, s1, 0, 0, 0);
            s8v kf3 = *(const s8v*)(Ksh + (16 + ln) * 64 + 32 + hi * 8);
            s1 = __builtin_amdgcn_mfma_f32_16x16x32_bf16(qa1, kf3, s1, 0, 0, 0);
        }

        // online softmax per owned row
        #pragma unroll
        for (int i = 0; i < 4; i++) {
            const int qrow = q0 + hi * 4 + i;
            float v0 = s0[i] * 0.125f;
            float v1 = s1[i] * 0.125f;
            if (k0 + ln > qrow)      v0 = -__builtin_inff();
            if (k0 + 16 + ln > qrow) v1 = -__builtin_inff();
            float mx = fmaxf(v0, v1);
            #pragma unroll
            for (int off = 8; off >= 1; off >>= 1) mx = fmaxf(mx, __shfl_xor(mx, off));
            const float mn = fmaxf(m_i[i], mx);
            const float alpha = __expf(m_i[i] - mn); // m_i=-inf only before 1st block (mx finite there)
            const float p0 = __expf(v0 - mn);
            const float p1 = __expf(v1 - mn);
            float rs = p0 + p1;
            #pragma unroll
            for (int off = 8; off >= 1; off >>= 1) rs += __shfl_xor(rs, off);
            l_i[i] = l_i[i] * alpha + rs;
            m_i[i] = mn;
            o[0][i] *= alpha; o[1][i] *= alpha; o[2][i] *= alpha; o[3][i] *= alpha;
            Psh[wave * 512 + (hi * 4 + i) * 32 + ln]      = bf_bits(p0);
            Psh[wave * 512 + (hi * 4 + i) * 32 + 16 + ln] = bf_bits(p1);
        }
        __syncthreads();

        // O += P * V  (P via LDS to get A-operand layout; V transposed for B-operand)
        s8v pa = *(const s8v*)(Psh + wave * 512 + ln * 32 + hi * 8);
        #pragma unroll
        for (int dt = 0; dt < 4; dt++) {
            s8v vb = *(const s8v*)(Vsh + (dt * 16 + ln) * 32 + hi * 8);
            o[dt] = __builtin_amdgcn_mfma_f32_16x16x32_bf16(pa, vb, o[dt], 0, 0, 0);
        }
    }

    #pragma unroll
    for (int dt = 0; dt < 4; dt++)
        #pragma unroll
        for (int i = 0; i < 4; i++) {
            const int qrow = q0 + hi * 4 + i;
            Y[base + (size_t)qrow * Csz + dt * 16 + ln] = bf_bits(o[dt][i] / l_i[i]);
        }
}

extern "C" void kernel_launch(void* const* d_in, const int* in_sizes, int n_in,
                              void* d_out, int out_size, void* d_ws, size_t ws_size,
                              hipStream_t stream) {
    const float* x  = (const float*)d_in[0];
    const float* Wq = (const float*)d_in[1];
    const float* bq = (const float*)d_in[2];
    const float* Wk = (const float*)d_in[3];
    const float* bk = (const float*)d_in[4];
    const float* Wv = (const float*)d_in[5];
    const float* bv = (const float*)d_in[6];
    const float* Wp = (const float*)d_in[7];
    const float* bp = (const float*)d_in[8];

    char* ws = (char*)d_ws;
    short* Xb  = (short*)(ws);                 // 8 MB
    short* Wqb = (short*)(ws + (8u  << 20));   // 2 MB each
    short* Wkb = (short*)(ws + (10u << 20));
    short* Wvb = (short*)(ws + (12u << 20));
    short* Wpb = (short*)(ws + (14u << 20));
    short* Qb  = (short*)(ws + (16u << 20));   // 8 MB each
    short* Kb  = (short*)(ws + (24u << 20));
    short* Vb  = (short*)(ws + (32u << 20));
    short* Yb  = (short*)(ws + (40u << 20));

    const int nx = Bsz * Tsz * Csz;      // 4194304
    const int nw = Csz * Csz;            // 1048576
    hipLaunchKernelGGL(cvt_kernel, dim3(nx / 1024), dim3(256), 0, stream, x,  Xb,  nx);
    hipLaunchKernelGGL(cvt_kernel, dim3(nw / 1024), dim3(256), 0, stream, Wq, Wqb, nw);
    hipLaunchKernelGGL(cvt_kernel, dim3(nw / 1024), dim3(256), 0, stream, Wk, Wkb, nw);
    hipLaunchKernelGGL(cvt_kernel, dim3(nw / 1024), dim3(256), 0, stream, Wv, Wvb, nw);
    hipLaunchKernelGGL(cvt_kernel, dim3(nw / 1024), dim3(256), 0, stream, Wp, Wpb, nw);

    const int M = Bsz * Tsz;  // 4096
    dim3 gg(M / 64, Csz / 64);
    hipLaunchKernelGGL((gemm_bias_kernel<0>), gg, dim3(256), 0, stream, Xb, Wqb, bq, (void*)Qb, M, Csz, Csz);
    hipLaunchKernelGGL((gemm_bias_kernel<0>), gg, dim3(256), 0, stream, Xb, Wkb, bk, (void*)Kb, M, Csz, Csz);
    hipLaunchKernelGGL((gemm_bias_kernel<0>), gg, dim3(256), 0, stream, Xb, Wvb, bv, (void*)Vb, M, Csz, Csz);

    hipLaunchKernelGGL(attn_kernel, dim3(Tsz / 64, Bsz * Hn), dim3(256), 0, stream, Qb, Kb, Vb, Yb);

    hipLaunchKernelGGL((gemm_bias_kernel<1>), gg, dim3(256), 0, stream, Yb, Wpb, bp, d_out, M, Csz, Csz);
}

// Round 2
// 335.447 us; speedup vs baseline: 1.8344x; 1.8344x over previous
//
#include <hip/hip_runtime.h>
#include <hip/hip_bf16.h>

#define Tsz 2048
#define Csz 1024
#define Hn 16

typedef short s8v __attribute__((ext_vector_type(8)));
typedef short s4v __attribute__((ext_vector_type(4)));
typedef float f4v __attribute__((ext_vector_type(4)));

#define QSCALE (0.125f * 1.44269504088896f)  // 1/sqrt(64) * log2(e), folded into Q

__device__ __forceinline__ short bf_bits(float x) {
    __hip_bfloat16 t = __float2bfloat16(x);
    return *reinterpret_cast<short*>(&t);
}

__device__ __forceinline__ void gload_lds(const void* g, void* l) {
    __builtin_amdgcn_global_load_lds(
        (const __attribute__((address_space(1))) void*)g,
        (__attribute__((address_space(3))) void*)l, 16, 0, 0);
}

// ---------------- fp32 -> bf16 conversion ----------------
__global__ void cvt_kernel(const float* __restrict__ in, short* __restrict__ out, int n) {
    int i = (blockIdx.x * blockDim.x + threadIdx.x) * 4;
    if (i >= n) return;
    float4 v = *(const float4*)(in + i);
    short4 o;
    o.x = bf_bits(v.x); o.y = bf_bits(v.y); o.z = bf_bits(v.z); o.w = bf_bits(v.w);
    *(short4*)(out + i) = o;
}

// ---------------- GEMM: out[m,n] = sum_k A[m,k]*W[n,k] + bias[n] ----------------
// LDS-tiled m97-style: BM=128, BN=64, BK=32; 256 threads (4 waves), wave = 64m x 32n.
// MODE: 0 = bf16 out, 1 = f32 out, 2 = bf16 out * QSCALE (for Q), 3 = bf16 out in Vt[b][h][d][T] layout.
template<int MODE>
__global__ __launch_bounds__(256) void gemm128(
    const short* __restrict__ A, const short* __restrict__ W,
    const float* __restrict__ bias, void* __restrict__ outp,
    int M, int N, int K)
{
    __shared__ __align__(16) short Ash[128 * 32];
    __shared__ __align__(16) short Bsh[64 * 32];

    const int tid = threadIdx.x, lane = tid & 63, wave = tid >> 6;
    const int ln = lane & 15, hi = lane >> 4;
    const int m0 = blockIdx.x * 128, n0 = blockIdx.y * 64;
    const int wmo = (wave >> 1) * 64, wno = (wave & 1) * 32;

    // staging: chunk c covers row c>>2, k-offset (c&3)*8 (16B)
    const short* Ag = A + (size_t)(m0 + (tid >> 2)) * K + (tid & 3) * 8;
    const short* Wg = W + (size_t)(n0 + (tid >> 2)) * K + (tid & 3) * 8;

    f4v acc[4][2];
    #pragma unroll
    for (int mt = 0; mt < 4; mt++)
        #pragma unroll
        for (int nt = 0; nt < 2; nt++)
            #pragma unroll
            for (int i = 0; i < 4; i++) acc[mt][nt][i] = 0.f;

    for (int k0 = 0; k0 < K; k0 += 32) {
        __syncthreads();
        gload_lds(Ag + k0, Ash + tid * 8);
        gload_lds(Ag + k0 + (size_t)64 * K, Ash + 2048 + tid * 8);
        gload_lds(Wg + k0, Bsh + tid * 8);
        __syncthreads();

        s8v af[4], bf_[2];
        #pragma unroll
        for (int mt = 0; mt < 4; mt++)
            af[mt] = *(const s8v*)(Ash + (wmo + mt * 16 + ln) * 32 + hi * 8);
        #pragma unroll
        for (int nt = 0; nt < 2; nt++)
            bf_[nt] = *(const s8v*)(Bsh + (wno + nt * 16 + ln) * 32 + hi * 8);
        #pragma unroll
        for (int mt = 0; mt < 4; mt++)
            #pragma unroll
            for (int nt = 0; nt < 2; nt++)
                acc[mt][nt] = __builtin_amdgcn_mfma_f32_16x16x32_bf16(af[mt], bf_[nt], acc[mt][nt], 0, 0, 0);
    }

    float bv[2];
    #pragma unroll
    for (int nt = 0; nt < 2; nt++) bv[nt] = bias[n0 + wno + nt * 16 + ln];

    if (MODE == 3) {
        // write transposed per head: Vt[((b*16+h)*64+d)*T + t]
        #pragma unroll
        for (int mt = 0; mt < 4; mt++)
            #pragma unroll
            for (int nt = 0; nt < 2; nt++) {
                const int ch = n0 + wno + nt * 16 + ln;       // channel
                const int tok0 = m0 + wmo + mt * 16 + hi * 4; // first of 4 tokens
                const int b = tok0 >> 11, t = tok0 & 2047;
                const int h = ch >> 6, d = ch & 63;
                s4v pk;
                #pragma unroll
                for (int i = 0; i < 4; i++) pk[i] = bf_bits(acc[mt][nt][i] + bv[nt]);
                *(s4v*)((short*)outp + (size_t)((b * Hn + h) * 64 + d) * Tsz + t) = pk;
            }
    } else {
        #pragma unroll
        for (int mt = 0; mt < 4; mt++)
            #pragma unroll
            for (int nt = 0; nt < 2; nt++)
                #pragma unroll
                for (int i = 0; i < 4; i++) {
                    const int row = m0 + wmo + mt * 16 + hi * 4 + i;
                    const int col = n0 + wno + nt * 16 + ln;
                    const float v = acc[mt][nt][i] + bv[nt];
                    if (MODE == 1)      ((float*)outp)[(size_t)row * N + col] = v;
                    else if (MODE == 2) ((short*)outp)[(size_t)row * N + col] = bf_bits(v * QSCALE);
                    else                ((short*)outp)[(size_t)row * N + col] = bf_bits(v);
                }
    }
}

// ---------------- Flash attention v2 (causal, no-max online softmax) ----------------
// Q,K,Y: [B,T,C] bf16; Vt: [B*H*64, T] bf16 (pre-transposed by V GEMM).
// Q is pre-scaled by 0.125*log2e, so p = exp2(q.k).
// Block: 256 threads = 4 waves; block owns 128 q rows; wave owns rows {q0+w*16..+15, q0+64+w*16..+15}.
__global__ __launch_bounds__(256) void attn2(
    const short* __restrict__ Q, const short* __restrict__ Kg,
    const short* __restrict__ Vt, short* __restrict__ Y)
{
    __shared__ __align__(16) short Ksh[64 * 64];        // [key][d]
    __shared__ __align__(16) short Vsh[64 * 64];        // [d][key]
    __shared__ __align__(16) short Psh[8 * 16 * 72];    // per (wave,mt): 16 rows x pitch 72

    const int tid = threadIdx.x, lane = tid & 63, wave = tid >> 6;
    const int ln = lane & 15, hi = lane >> 4;
    const int qt = (int)gridDim.x - 1 - (int)blockIdx.x;  // heavy tiles dispatched first
    const int q0 = qt * 128;
    const int bh = blockIdx.y;
    const size_t base = (size_t)(bh >> 4) * Tsz * Csz + (size_t)(bh & 15) * 64;
    const size_t vtbase = (size_t)bh * 64 * Tsz;

    // Q fragments (A-operand layout), resident all kernel
    s8v qa[2][2];
    #pragma unroll
    for (int mt = 0; mt < 2; mt++)
        #pragma unroll
        for (int kk = 0; kk < 2; kk++)
            qa[mt][kk] = *(const s8v*)(Q + base + (size_t)(q0 + mt * 64 + wave * 16 + ln) * Csz + kk * 32 + hi * 8);

    f4v o[2][4], lacc[2];
    #pragma unroll
    for (int mt = 0; mt < 2; mt++) {
        #pragma unroll
        for (int i = 0; i < 4; i++) lacc[mt][i] = 0.f;
        #pragma unroll
        for (int dt = 0; dt < 4; dt++)
            #pragma unroll
            for (int i = 0; i < 4; i++) o[mt][dt][i] = 0.f;
    }

    s8v ones;
    #pragma unroll
    for (int j = 0; j < 8; j++) ones[j] = (short)0x3F80;  // bf16 1.0

    // staging: chunk = tid: row tid>>3 (0..31), col (tid&7)*8; pass 2 adds 32 rows
    const short* Kg0 = Kg + base + (size_t)(tid >> 3) * Csz + (tid & 7) * 8;
    const short* Vg0 = Vt + vtbase + (size_t)(tid >> 3) * Tsz + (tid & 7) * 8;

    const int nkb = 2 * qt + 2;
    for (int kb = 0; kb < nkb; kb++) {
        const int k0 = kb * 64;
        __syncthreads();
        gload_lds(Kg0 + (size_t)k0 * Csz, Ksh + tid * 8);
        gload_lds(Kg0 + (size_t)(k0 + 32) * Csz, Ksh + 2048 + tid * 8);
        gload_lds(Vg0 + k0, Vsh + tid * 8);
        gload_lds(Vg0 + (size_t)32 * Tsz + k0, Vsh + 2048 + tid * 8);
        __syncthreads();

        s8v kf[2][4], vb[2][4];
        #pragma unroll
        for (int nt = 0; nt < 4; nt++)
            #pragma unroll
            for (int kk = 0; kk < 2; kk++) {
                kf[kk][nt] = *(const s8v*)(Ksh + (nt * 16 + ln) * 64 + kk * 32 + hi * 8);
                vb[kk][nt] = *(const s8v*)(Vsh + (nt * 16 + ln) * 64 + kk * 32 + hi * 8);
            }

        const int mt_lo = (kb == nkb - 1) ? 1 : 0;  // mt0 fully masked on last tile
        for (int mt = mt_lo; mt < 2; mt++) {
            const bool dg = (kb == nkb - 2 + mt);   // diagonal tile for this m-tile
            f4v s[4];
            #pragma unroll
            for (int nt = 0; nt < 4; nt++) {
                #pragma unroll
                for (int i = 0; i < 4; i++) s[nt][i] = 0.f;
                s[nt] = __builtin_amdgcn_mfma_f32_16x16x32_bf16(qa[mt][0], kf[0][nt], s[nt], 0, 0, 0);
                s[nt] = __builtin_amdgcn_mfma_f32_16x16x32_bf16(qa[mt][1], kf[1][nt], s[nt], 0, 0, 0);
            }
            short* Pw = Psh + (wave * 2 + mt) * 1152;
            #pragma unroll
            for (int i = 0; i < 4; i++) {
                const int rrel = wave * 16 + hi * 4 + i;  // q row within 64-block
                #pragma unroll
                for (int nt = 0; nt < 4; nt++) {
                    float sv = s[nt][i];
                    if (dg && (nt * 16 + ln) > rrel) sv = -1.0e38f;
                    Pw[(hi * 4 + i) * 72 + nt * 16 + ln] = bf_bits(exp2f(sv));
                }
            }
            const s8v pa0 = *(const s8v*)(Pw + ln * 72 + hi * 8);
            const s8v pa1 = *(const s8v*)(Pw + ln * 72 + 32 + hi * 8);
            #pragma unroll
            for (int dt = 0; dt < 4; dt++) {
                o[mt][dt] = __builtin_amdgcn_mfma_f32_16x16x32_bf16(pa0, vb[0][dt], o[mt][dt], 0, 0, 0);
                o[mt][dt] = __builtin_amdgcn_mfma_f32_16x16x32_bf16(pa1, vb[1][dt], o[mt][dt], 0, 0, 0);
            }
            lacc[mt] = __builtin_amdgcn_mfma_f32_16x16x32_bf16(pa0, ones, lacc[mt], 0, 0, 0);
            lacc[mt] = __builtin_amdgcn_mfma_f32_16x16x32_bf16(pa1, ones, lacc[mt], 0, 0, 0);
        }
    }

    #pragma unroll
    for (int mt = 0; mt < 2; mt++) {
        float inv[4];
        #pragma unroll
        for (int i = 0; i < 4; i++) inv[i] = 1.0f / lacc[mt][i];
        #pragma unroll
        for (int dt = 0; dt < 4; dt++)
            #pragma unroll
            for (int i = 0; i < 4; i++) {
                const int qrow = q0 + mt * 64 + wave * 16 + hi * 4 + i;
                Y[base + (size_t)qrow * Csz + dt * 16 + ln] = bf_bits(o[mt][dt][i] * inv[i]);
            }
    }
}

extern "C" void kernel_launch(void* const* d_in, const int* in_sizes, int n_in,
                              void* d_out, int out_size, void* d_ws, size_t ws_size,
                              hipStream_t stream) {
    const float* x  = (const float*)d_in[0];
    const float* Wq = (const float*)d_in[1];
    const float* bq = (const float*)d_in[2];
    const float* Wk = (const float*)d_in[3];
    const float* bk = (const float*)d_in[4];
    const float* Wv = (const float*)d_in[5];
    const float* bv = (const float*)d_in[6];
    const float* Wp = (const float*)d_in[7];
    const float* bp = (const float*)d_in[8];

    char* ws = (char*)d_ws;
    short* Xb  = (short*)(ws);                 // 8 MB
    short* Wqb = (short*)(ws + (8u  << 20));   // 2 MB each
    short* Wkb = (short*)(ws + (10u << 20));
    short* Wvb = (short*)(ws + (12u << 20));
    short* Wpb = (short*)(ws + (14u << 20));
    short* Qb  = (short*)(ws + (16u << 20));   // 8 MB each
    short* Kb  = (short*)(ws + (24u << 20));
    short* Vtb = (short*)(ws + (32u << 20));   // V transposed per head [B*H*64, T]
    short* Yb  = (short*)(ws + (40u << 20));

    const int nx = 2 * Tsz * Csz;        // 4194304
    const int nw = Csz * Csz;            // 1048576
    hipLaunchKernelGGL(cvt_kernel, dim3(nx / 1024), dim3(256), 0, stream, x,  Xb,  nx);
    hipLaunchKernelGGL(cvt_kernel, dim3(nw / 1024), dim3(256), 0, stream, Wq, Wqb, nw);
    hipLaunchKernelGGL(cvt_kernel, dim3(nw / 1024), dim3(256), 0, stream, Wk, Wkb, nw);
    hipLaunchKernelGGL(cvt_kernel, dim3(nw / 1024), dim3(256), 0, stream, Wv, Wvb, nw);
    hipLaunchKernelGGL(cvt_kernel, dim3(nw / 1024), dim3(256), 0, stream, Wp, Wpb, nw);

    const int M = 2 * Tsz;  // 4096
    dim3 gg(M / 128, Csz / 64);
    hipLaunchKernelGGL((gemm128<2>), gg, dim3(256), 0, stream, Xb, Wqb, bq, (void*)Qb,  M, Csz, Csz);
    hipLaunchKernelGGL((gemm128<0>), gg, dim3(256), 0, stream, Xb, Wkb, bk, (void*)Kb,  M, Csz, Csz);
    hipLaunchKernelGGL((gemm128<3>), gg, dim3(256), 0, stream, Xb, Wvb, bv, (void*)Vtb, M, Csz, Csz);

    hipLaunchKernelGGL(attn2, dim3(Tsz / 128, 2 * Hn), dim3(256), 0, stream, Qb, Kb, Vtb, Yb);

    hipLaunchKernelGGL((gemm128<1>), gg, dim3(256), 0, stream, Yb, Wpb, bp, d_out, M, Csz, Csz);
}

// Round 4
// 190.359 us; speedup vs baseline: 3.2325x; 1.7622x over previous
//
#include <hip/hip_runtime.h>
#include <hip/hip_bf16.h>

#define Tsz 2048
#define Csz 1024
#define Hn 16

typedef short s8v __attribute__((ext_vector_type(8)));
typedef short s4v __attribute__((ext_vector_type(4)));
typedef float f4v __attribute__((ext_vector_type(4)));

#define QSCALE (0.125f * 1.44269504088896f)  // 1/sqrt(64) * log2(e), folded into Q

__device__ __forceinline__ short bf_bits(float x) {
    __hip_bfloat16 t = __float2bfloat16(x);
    return *reinterpret_cast<short*>(&t);
}

__device__ __forceinline__ void gload_lds(const void* g, void* l) {
    __builtin_amdgcn_global_load_lds(
        (const __attribute__((address_space(1))) void*)g,
        (__attribute__((address_space(3))) void*)l, 16, 0, 0);
}

// ---------------- fused fp32 -> bf16 conversion (x + 4 weights) ----------------
__global__ void cvt5(const float* __restrict__ x, const float* __restrict__ wq,
                     const float* __restrict__ wk, const float* __restrict__ wv,
                     const float* __restrict__ wp,
                     short* __restrict__ xo, short* __restrict__ qo,
                     short* __restrict__ ko, short* __restrict__ vo,
                     short* __restrict__ po) {
    const int y = blockIdx.y;
    const float* in; short* out; int n;
    switch (y) {
        case 0: in = x;  out = xo; n = 2 * Tsz * Csz; break;
        case 1: in = wq; out = qo; n = Csz * Csz; break;
        case 2: in = wk; out = ko; n = Csz * Csz; break;
        case 3: in = wv; out = vo; n = Csz * Csz; break;
        default: in = wp; out = po; n = Csz * Csz; break;
    }
    int i = (blockIdx.x * blockDim.x + threadIdx.x) * 4;
    if (i >= n) return;
    float4 v = *(const float4*)(in + i);
    short4 o;
    o.x = bf_bits(v.x); o.y = bf_bits(v.y); o.z = bf_bits(v.z); o.w = bf_bits(v.w);
    *(short4*)(out + i) = o;
}

// ---------------- fused QKV GEMM (m97 structure) ----------------
// out[m,n] = sum_k X[m,k]*W[n,k] + b[n].  BM=BN=128, BK=32, 256 thr, wave=64x64.
// z=0: Q (bf16, *QSCALE), z=1: K (bf16), z=2: V -> Vt[(b*1024+ch)*T + t] (bf16).
__global__ __launch_bounds__(256, 2) void qkv_gemm(
    const short* __restrict__ X,
    const short* __restrict__ Wq, const short* __restrict__ Wk, const short* __restrict__ Wv,
    const float* __restrict__ bq, const float* __restrict__ bk, const float* __restrict__ bv,
    short* __restrict__ Qo, short* __restrict__ Ko, short* __restrict__ Vto)
{
    const int z = blockIdx.z;
    const short* W = (z == 0) ? Wq : (z == 1) ? Wk : Wv;
    const float* bias = (z == 0) ? bq : (z == 1) ? bk : bv;

    __shared__ __align__(16) short Ash[128 * 32];
    __shared__ __align__(16) short Bsh[128 * 32];

    const int tid = threadIdx.x, lane = tid & 63, wave = tid >> 6;
    const int ln = lane & 15, hi = lane >> 4;
    const int m0 = blockIdx.x * 128, n0 = blockIdx.y * 128;
    const int wm = (wave >> 1) * 64, wn = (wave & 1) * 64;

    const short* Ag = X + (size_t)(m0 + (tid >> 2)) * Csz + (tid & 3) * 8;
    const short* Bg = W + (size_t)(n0 + (tid >> 2)) * Csz + (tid & 3) * 8;

    f4v acc[4][4];
    #pragma unroll
    for (int mt = 0; mt < 4; mt++)
        #pragma unroll
        for (int nt = 0; nt < 4; nt++)
            #pragma unroll
            for (int i = 0; i < 4; i++) acc[mt][nt][i] = 0.f;

    for (int k0 = 0; k0 < Csz; k0 += 32) {
        __syncthreads();
        gload_lds(Ag + k0, Ash + tid * 8);
        gload_lds(Ag + k0 + (size_t)64 * Csz, Ash + 2048 + tid * 8);
        gload_lds(Bg + k0, Bsh + tid * 8);
        gload_lds(Bg + k0 + (size_t)64 * Csz, Bsh + 2048 + tid * 8);
        __syncthreads();

        s8v af[4], bfr[4];
        #pragma unroll
        for (int mt = 0; mt < 4; mt++)
            af[mt] = *(const s8v*)(Ash + (wm + mt * 16 + ln) * 32 + hi * 8);
        #pragma unroll
        for (int nt = 0; nt < 4; nt++)
            bfr[nt] = *(const s8v*)(Bsh + (wn + nt * 16 + ln) * 32 + hi * 8);
        #pragma unroll
        for (int mt = 0; mt < 4; mt++)
            #pragma unroll
            for (int nt = 0; nt < 4; nt++)
                acc[mt][nt] = __builtin_amdgcn_mfma_f32_16x16x32_bf16(af[mt], bfr[nt], acc[mt][nt], 0, 0, 0);
    }

    const float scale = (z == 0) ? QSCALE : 1.0f;
    short* out = (z == 0) ? Qo : Ko;

    #pragma unroll
    for (int nt = 0; nt < 4; nt++) {
        const int col = n0 + wn + nt * 16 + ln;
        const float bvv = bias[col];
        #pragma unroll
        for (int mt = 0; mt < 4; mt++) {
            const int row0 = m0 + wm + mt * 16 + hi * 4;
            if (z == 2) {
                const int b = row0 >> 11, t = row0 & 2047;
                s4v pk;
                #pragma unroll
                for (int i = 0; i < 4; i++) pk[i] = bf_bits(acc[mt][nt][i] + bvv);
                *(s4v*)(Vto + (size_t)(b * 1024 + col) * Tsz + t) = pk;
            } else {
                #pragma unroll
                for (int i = 0; i < 4; i++)
                    out[(size_t)(row0 + i) * Csz + col] = bf_bits((acc[mt][nt][i] + bvv) * scale);
            }
        }
    }
}

// ---------------- output projection GEMM (f32 out) ----------------
__global__ __launch_bounds__(256, 2) void proj_gemm(
    const short* __restrict__ A, const short* __restrict__ W,
    const float* __restrict__ bias, float* __restrict__ out)
{
    __shared__ __align__(16) short Ash[128 * 32];
    __shared__ __align__(16) short Bsh[128 * 32];

    const int tid = threadIdx.x, lane = tid & 63, wave = tid >> 6;
    const int ln = lane & 15, hi = lane >> 4;
    const int m0 = blockIdx.x * 128, n0 = blockIdx.y * 128;
    const int wm = (wave >> 1) * 64, wn = (wave & 1) * 64;

    const short* Ag = A + (size_t)(m0 + (tid >> 2)) * Csz + (tid & 3) * 8;
    const short* Bg = W + (size_t)(n0 + (tid >> 2)) * Csz + (tid & 3) * 8;

    f4v acc[4][4];
    #pragma unroll
    for (int mt = 0; mt < 4; mt++)
        #pragma unroll
        for (int nt = 0; nt < 4; nt++)
            #pragma unroll
            for (int i = 0; i < 4; i++) acc[mt][nt][i] = 0.f;

    for (int k0 = 0; k0 < Csz; k0 += 32) {
        __syncthreads();
        gload_lds(Ag + k0, Ash + tid * 8);
        gload_lds(Ag + k0 + (size_t)64 * Csz, Ash + 2048 + tid * 8);
        gload_lds(Bg + k0, Bsh + tid * 8);
        gload_lds(Bg + k0 + (size_t)64 * Csz, Bsh + 2048 + tid * 8);
        __syncthreads();

        s8v af[4], bfr[4];
        #pragma unroll
        for (int mt = 0; mt < 4; mt++)
            af[mt] = *(const s8v*)(Ash + (wm + mt * 16 + ln) * 32 + hi * 8);
        #pragma unroll
        for (int nt = 0; nt < 4; nt++)
            bfr[nt] = *(const s8v*)(Bsh + (wn + nt * 16 + ln) * 32 + hi * 8);
        #pragma unroll
        for (int mt = 0; mt < 4; mt++)
            #pragma unroll
            for (int nt = 0; nt < 4; nt++)
                acc[mt][nt] = __builtin_amdgcn_mfma_f32_16x16x32_bf16(af[mt], bfr[nt], acc[mt][nt], 0, 0, 0);
    }

    #pragma unroll
    for (int nt = 0; nt < 4; nt++) {
        const int col = n0 + wn + nt * 16 + ln;
        const float bvv = bias[col];
        #pragma unroll
        for (int mt = 0; mt < 4; mt++)
            #pragma unroll
            for (int i = 0; i < 4; i++)
                out[(size_t)(m0 + wm + mt * 16 + hi * 4 + i) * Csz + col] = acc[mt][nt][i] + bvv;
    }
}

// ---------------- Flash attention v4 (transposed form, LDS P-relayout) ----------------
// Q,K: [B,T,C] bf16; Vt: [B*H*64, T] bf16; Y: [B,T,C] bf16.
// Computes St = K*Q^T and O^T = Vt*P^T; P^T re-laid out via wave-private LDS:
//   writer lane (ln,hi) holds P^T[key=nt*16+hi*4+{0..3}][q=ln] -> ds_write_b64 to Pq[q][key]
//   reader lane (ln,hi) pulls B-frag P^T[key=kk*32+hi*8+j][q=ln] -> ds_read_b128.
// Block: 4 waves; handles q-tiles p and 31-p (64 rows each); wave owns 16 rows of both.
__global__ __launch_bounds__(256, 2) void attn4(
    const short* __restrict__ Q, const short* __restrict__ Kg,
    const short* __restrict__ Vt, short* __restrict__ Y)
{
    __shared__ __align__(16) short Ksh[64 * 72];   // [key][d], pitch 72
    __shared__ __align__(16) short Vsh[64 * 72];   // [d][key], pitch 72
    __shared__ __align__(16) short Psh[4][16 * 72]; // per-wave Pq[q][key], pitch 72

    const int tid = threadIdx.x, lane = tid & 63, wave = tid >> 6;
    const int ln = lane & 15, hi = lane >> 4;
    const int p = blockIdx.x;                // pair 0..15
    const int qts[2] = { p, 31 - p };        // light, heavy 64-row q-tiles
    const int bh = blockIdx.y;
    const size_t base = (size_t)(bh >> 4) * Tsz * Csz + (size_t)(bh & 15) * 64;
    const size_t vtbase = (size_t)bh * 64 * Tsz;
    const int qrel = wave * 16 + ln;         // within-tile q row (MFMA n-col)
    short* Pq = Psh[wave];

    s8v qf[2][2];
    #pragma unroll
    for (int t = 0; t < 2; t++)
        #pragma unroll
        for (int kk = 0; kk < 2; kk++)
            qf[t][kk] = *(const s8v*)(Q + base + (size_t)(qts[t] * 64 + qrel) * Csz + kk * 32 + hi * 8);

    f4v o[2][4], lacc[2];
    #pragma unroll
    for (int t = 0; t < 2; t++) {
        #pragma unroll
        for (int i = 0; i < 4; i++) lacc[t][i] = 0.f;
        #pragma unroll
        for (int dt = 0; dt < 4; dt++)
            #pragma unroll
            for (int i = 0; i < 4; i++) o[t][dt][i] = 0.f;
    }

    s8v ones;
    #pragma unroll
    for (int j = 0; j < 8; j++) ones[j] = (short)0x3F80;  // bf16 1.0

    const int sr = tid >> 2, sc = (tid & 3) * 16;
    const short* Kp = Kg + base + (size_t)sr * Csz + sc;
    const short* Vp = Vt + vtbase + (size_t)sr * Tsz + sc;
    short* KshW = Ksh + sr * 72 + sc;
    short* VshW = Vsh + sr * 72 + sc;

    const int nkb = qts[1] + 1;
    for (int kb = 0; kb < nkb; kb++) {
        const int k0 = kb * 64;
        const s8v ka = *(const s8v*)(Kp + (size_t)k0 * Csz);
        const s8v kb2 = *(const s8v*)(Kp + (size_t)k0 * Csz + 8);
        const s8v va = *(const s8v*)(Vp + k0);
        const s8v vb2 = *(const s8v*)(Vp + k0 + 8);
        __syncthreads();
        *(s8v*)(KshW) = ka; *(s8v*)(KshW + 8) = kb2;
        *(s8v*)(VshW) = va; *(s8v*)(VshW + 8) = vb2;
        __syncthreads();

        s8v kf[2][4], vf[2][4];
        #pragma unroll
        for (int nt = 0; nt < 4; nt++)
            #pragma unroll
            for (int kk = 0; kk < 2; kk++) {
                kf[kk][nt] = *(const s8v*)(Ksh + (nt * 16 + ln) * 72 + kk * 32 + hi * 8);
                vf[kk][nt] = *(const s8v*)(Vsh + (nt * 16 + ln) * 72 + kk * 32 + hi * 8);
            }

        #pragma unroll
        for (int t = 0; t < 2; t++) {
            if (t == 0 && kb > qts[0]) continue;   // light tile done (uniform branch)
            const bool dg = (kb == qts[t]);        // diagonal block for this tile

            f4v s[4];
            #pragma unroll
            for (int nt = 0; nt < 4; nt++) {
                #pragma unroll
                for (int i = 0; i < 4; i++) s[nt][i] = 0.f;
                s[nt] = __builtin_amdgcn_mfma_f32_16x16x32_bf16(kf[0][nt], qf[t][0], s[nt], 0, 0, 0);
                s[nt] = __builtin_amdgcn_mfma_f32_16x16x32_bf16(kf[1][nt], qf[t][1], s[nt], 0, 0, 0);
            }

            // P^T write: lane holds keys nt*16+hi*4+{0..3} for q=ln
            #pragma unroll
            for (int nt = 0; nt < 4; nt++) {
                float pv[4];
                #pragma unroll
                for (int i = 0; i < 4; i++) pv[i] = exp2f(s[nt][i]);
                if (dg) {
                    const int kr = nt * 16 + hi * 4;
                    #pragma unroll
                    for (int i = 0; i < 4; i++)
                        if (kr + i > qrel) pv[i] = 0.f;
                }
                s4v w;
                #pragma unroll
                for (int i = 0; i < 4; i++) w[i] = bf_bits(pv[i]);
                *(s4v*)(Pq + ln * 72 + nt * 16 + hi * 4) = w;  // ds_write_b64
            }
            // B-frag read: keys kk*32+hi*8+{0..7} for q=ln
            const s8v pb0 = *(const s8v*)(Pq + ln * 72 + hi * 8);
            const s8v pb1 = *(const s8v*)(Pq + ln * 72 + 32 + hi * 8);

            #pragma unroll
            for (int dt = 0; dt < 4; dt++) {
                o[t][dt] = __builtin_amdgcn_mfma_f32_16x16x32_bf16(vf[0][dt], pb0, o[t][dt], 0, 0, 0);
                o[t][dt] = __builtin_amdgcn_mfma_f32_16x16x32_bf16(vf[1][dt], pb1, o[t][dt], 0, 0, 0);
            }
            lacc[t] = __builtin_amdgcn_mfma_f32_16x16x32_bf16(ones, pb0, lacc[t], 0, 0, 0);
            lacc[t] = __builtin_amdgcn_mfma_f32_16x16x32_bf16(ones, pb1, lacc[t], 0, 0, 0);
        }
    }

    #pragma unroll
    for (int t = 0; t < 2; t++) {
        const float inv = 1.0f / lacc[t][0];
        const int qrow = qts[t] * 64 + qrel;
        #pragma unroll
        for (int dt = 0; dt < 4; dt++) {
            s4v w;
            #pragma unroll
            for (int i = 0; i < 4; i++) w[i] = bf_bits(o[t][dt][i] * inv);
            *(s4v*)(Y + base + (size_t)qrow * Csz + dt * 16 + hi * 4) = w;
        }
    }
}

extern "C" void kernel_launch(void* const* d_in, const int* in_sizes, int n_in,
                              void* d_out, int out_size, void* d_ws, size_t ws_size,
                              hipStream_t stream) {
    const float* x  = (const float*)d_in[0];
    const float* Wq = (const float*)d_in[1];
    const float* bq = (const float*)d_in[2];
    const float* Wk = (const float*)d_in[3];
    const float* bk = (const float*)d_in[4];
    const float* Wv = (const float*)d_in[5];
    const float* bv = (const float*)d_in[6];
    const float* Wp = (const float*)d_in[7];
    const float* bp = (const float*)d_in[8];

    char* ws = (char*)d_ws;
    short* Xb  = (short*)(ws);                 // 8 MB
    short* Wqb = (short*)(ws + (8u  << 20));   // 2 MB each
    short* Wkb = (short*)(ws + (10u << 20));
    short* Wvb = (short*)(ws + (12u << 20));
    short* Wpb = (short*)(ws + (14u << 20));
    short* Qb  = (short*)(ws + (16u << 20));   // 8 MB each
    short* Kb  = (short*)(ws + (24u << 20));
    short* Vtb = (short*)(ws + (32u << 20));   // V transposed per head [B*H*64, T]
    short* Yb  = (short*)(ws + (40u << 20));

    hipLaunchKernelGGL(cvt5, dim3(4096, 5), dim3(256), 0, stream,
                       x, Wq, Wk, Wv, Wp, Xb, Wqb, Wkb, Wvb, Wpb);

    hipLaunchKernelGGL(qkv_gemm, dim3(32, 8, 3), dim3(256), 0, stream,
                       Xb, Wqb, Wkb, Wvb, bq, bk, bv, Qb, Kb, Vtb);

    hipLaunchKernelGGL(attn4, dim3(16, 32), dim3(256), 0, stream, Qb, Kb, Vtb, Yb);

    hipLaunchKernelGGL(proj_gemm, dim3(32, 8), dim3(256), 0, stream, Yb, Wpb, bp, (float*)d_out);
}